// Round 2
// baseline (1817.758 us; speedup 1.0000x reference)
//
#include <hip/hip_runtime.h>
#include <hip/hip_bf16.h>
#include <math.h>

#define SQ 1024       // sequence length
#define CS 768        // channels
#define CZ 128        // z channels
#define DD 32         // head dim
#define NH 24         // heads
#define EPSV 1e-5f

typedef __hip_bfloat16 bf16;

__device__ __forceinline__ float b2f(bf16 x) { return __bfloat162float(x); }
__device__ __forceinline__ bf16 f2b(float x) { return __float2bfloat16(x); }

// ---------------------------------------------------------------- k_adaln
// emb[b][o] = silu(t[b]) @ w_adaln[:,o] + b_adaln[o]   (o < 2304)
__global__ __launch_bounds__(256) void k_adaln(const float* t, const float* w,
                                               const float* bias, float* emb) {
    __shared__ float st[CS];
    int b = blockIdx.y;
    int o = blockIdx.x * 256 + threadIdx.x;
    for (int c = threadIdx.x; c < CS; c += 256) {
        float x = t[b * CS + c];
        st[c] = x / (1.0f + __expf(-x));
    }
    __syncthreads();
    float acc = bias[o];
    for (int c = 0; c < CS; ++c)
        acc += st[c] * w[(size_t)c * (3 * CS) + o];
    emb[(size_t)b * 3 * CS + o] = acc;
}

// ---------------------------------------------------------------- k_bsnorm
// bsn[b,s,c] = LN(bs[b,s,:])[c] * (1+scale[b,c]) + shift[b,c]
__global__ __launch_bounds__(256) void k_bsnorm(const float* bs, const float* emb,
                                                float* bsn) {
    int row = blockIdx.x;              // b*SQ + s
    int b = row >> 10;
    const float* x = bs + (size_t)row * CS;
    float v[3], s1 = 0.f, s2 = 0.f;
    #pragma unroll
    for (int i = 0; i < 3; i++) {
        float f = x[threadIdx.x + i * 256];
        v[i] = f; s1 += f; s2 += f * f;
    }
    __shared__ float red[8];
    for (int off = 32; off; off >>= 1) { s1 += __shfl_down(s1, off); s2 += __shfl_down(s2, off); }
    int wid = threadIdx.x >> 6;
    if ((threadIdx.x & 63) == 0) { red[wid] = s1; red[wid + 4] = s2; }
    __syncthreads();
    s1 = red[0] + red[1] + red[2] + red[3];
    s2 = red[4] + red[5] + red[6] + red[7];
    float mu = s1 * (1.0f / CS);
    float var = s2 * (1.0f / CS) - mu * mu;
    float rs = rsqrtf(var + EPSV);
    const float* sh = emb + (size_t)b * 3 * CS;
    float* o = bsn + (size_t)row * CS;
    #pragma unroll
    for (int i = 0; i < 3; i++) {
        int c = threadIdx.x + i * 256;
        o[c] = (v[i] - mu) * rs * (1.0f + sh[CS + c]) + sh[c];
    }
}

// ---------------------------------------------------------------- k_gemm_qkv
// C[2048 x 768] = A(fp32) @ W(fp32, [k][n] row-major); store to (b,h,s,d) fp32
__global__ __launch_bounds__(256) void k_gemm_qkv(const float* A, const float* W,
                                                  float* out) {
    __shared__ float As[16][68];   // [k][m]
    __shared__ float Bs[16][68];   // [k][n]
    int t = threadIdx.x;
    int m0g = blockIdx.x * 64;
    int n0g = blockIdx.y * 64;
    int mg = t >> 4, ng = t & 15;
    float acc[4][4] = {};
    for (int k0 = 0; k0 < CS; k0 += 16) {
        {   // stage A 64x16
            int kk = t & 15, mm = t >> 4;
            #pragma unroll
            for (int r = 0; r < 4; r++)
                As[kk][mm + r * 16] = A[(size_t)(m0g + mm + r * 16) * CS + k0 + kk];
            // stage W 16x64 (float4)
            int nn = (t & 15) * 4, kb = t >> 4;
            float4 w4 = *(const float4*)&W[(size_t)(k0 + kb) * CS + n0g + nn];
            *(float4*)&Bs[kb][nn] = w4;
        }
        __syncthreads();
        #pragma unroll
        for (int kk = 0; kk < 16; kk++) {
            float4 a4 = *(const float4*)&As[kk][mg * 4];
            float4 b4 = *(const float4*)&Bs[kk][ng * 4];
            float a[4] = {a4.x, a4.y, a4.z, a4.w};
            float bv[4] = {b4.x, b4.y, b4.z, b4.w};
            #pragma unroll
            for (int ii = 0; ii < 4; ii++)
                #pragma unroll
                for (int jj = 0; jj < 4; jj++)
                    acc[ii][jj] += a[ii] * bv[jj];
        }
        __syncthreads();
    }
    #pragma unroll
    for (int ii = 0; ii < 4; ii++) {
        int r = m0g + mg * 4 + ii;
        int b = r >> 10, s = r & 1023;
        #pragma unroll
        for (int jj = 0; jj < 4; jj++) {
            int c = n0g + ng * 4 + jj;
            int h = c >> 5, d = c & 31;
            out[(((size_t)b * NH + h) * SQ + s) * DD + d] = acc[ii][jj];
        }
    }
}

// ---------------------------------------------------------------- k_rms
// in-place RMS over D=32 groups of (b,h,s)
__global__ __launch_bounds__(256) void k_rms(float* x, const float* w) {
    int g = blockIdx.x * 8 + (threadIdx.x >> 5);
    int d = threadIdx.x & 31;
    float* p = x + (size_t)g * DD + d;
    float v = *p;
    float s = v * v;
    for (int off = 16; off; off >>= 1) s += __shfl_xor(s, off, 32);
    float rs = rsqrtf(s * (1.0f / DD) + EPSV);
    *p = v * rs * w[d];
}

// ---------------------------------------------------------------- k_zbias
// zbias[h, i, j] = bf16( sum_c (LN(z[i,j,:])[c]*lnw[c]+lnb[c]) * wz[c,h] + mask )
// one thread per (i,j); two passes over z row (2nd pass L1/L2-hot);
// wz/lnw/lnb via wave-uniform (scalar) loads
__global__ __launch_bounds__(256) void k_zbias(const float* z, const int* zmask,
                                               const float* wz, const float* lnw,
                                               const float* lnb, bf16* zbias) {
    size_t g = (size_t)blockIdx.x * 256 + threadIdx.x;
    const float4* zr = (const float4*)(z + g * CZ);
    float s1 = 0.f, s2 = 0.f;
    #pragma unroll
    for (int i = 0; i < 32; i++) {
        float4 f = zr[i];
        s1 += f.x + f.y + f.z + f.w;
        s2 += f.x * f.x + f.y * f.y + f.z * f.z + f.w * f.w;
    }
    float mu = s1 * (1.0f / CZ);
    float var = s2 * (1.0f / CZ) - mu * mu;
    float rs = rsqrtf(var + EPSV);
    float acc[NH];
    #pragma unroll
    for (int h = 0; h < NH; h++) acc[h] = 0.f;
    for (int i = 0; i < 32; i++) {
        float4 f = zr[i];
        float e[4] = {f.x, f.y, f.z, f.w};
        #pragma unroll
        for (int u = 0; u < 4; u++) {
            int c = i * 4 + u;
            float zn = (e[u] - mu) * rs * lnw[c] + lnb[c];
            #pragma unroll
            for (int h = 0; h < NH; h++) acc[h] += zn * wz[c * NH + h];
        }
    }
    float mb = (zmask[g] > 0) ? 0.0f : -1.0e9f;
    size_t SS = (size_t)SQ * SQ;
    #pragma unroll
    for (int h = 0; h < NH; h++)
        zbias[(size_t)h * SS + g] = f2b(acc[h] + mb);
}

// ---------------------------------------------------------------- k_attn
// flash attention per (b,h, 64-row q tile). q,k,v fp32 (b,h,s,d).
__global__ __launch_bounds__(256) void k_attn(const float* q, const float* k,
                                              const float* v, const bf16* zbias,
                                              const float* beta, float* attn_out) {
    int qt = blockIdx.x;   // 0..15
    int bh = blockIdx.y;   // 0..47
    int b = bh / NH, h = bh % NH;
    __shared__ float Qt[DD][68];   // [d][i]
    __shared__ float Kt[DD][68];   // [d][j]
    __shared__ float Vt[64][36];   // [j][d]
    __shared__ float Pt[64][68];   // [j][i]
    __shared__ float m_l[64], l_l[64], al_l[64];
    int t = threadIdx.x;
    const float scale = 0.17677669529663687f;   // 1/sqrt(32)
    const float* qb = q + ((size_t)bh * SQ + qt * 64) * DD;
    for (int i = t; i < 64 * DD; i += 256) {
        int r = i / DD, d = i % DD;
        Qt[d][r] = qb[i] * scale;
    }
    if (t < 64) { m_l[t] = -3.0e38f; l_l[t] = 0.f; }
    float O[2][4] = {};
    int ig = t >> 4, jg = t & 15;     // score mapping: rows ig*4.., cols jg*4..
    int ig2 = t >> 3, dg = t & 7;     // PV mapping: rows ig2*2.., d dg*4..
    size_t SS = (size_t)SQ * SQ;
    __syncthreads();
    for (int kt = 0; kt < 16; kt++) {
        const float* kb = k + ((size_t)bh * SQ + kt * 64) * DD;
        const float* vb = v + ((size_t)bh * SQ + kt * 64) * DD;
        for (int i = t; i < 64 * DD; i += 256) {
            int r = i / DD, d = i % DD;
            Kt[d][r] = kb[i];
            Vt[r][d] = vb[i];
        }
        __syncthreads();
        // ---- scores (4x4 per thread) with bias
        float sc[4][4];
        size_t ibase = (size_t)(qt * 64 + ig * 4);
        int jbase = kt * 64 + jg * 4;
        #pragma unroll
        for (int ii = 0; ii < 4; ii++) {
            size_t ro = (ibase + ii) * SQ + jbase;
            union { unsigned long long u; bf16 hh[4]; } zz;
            zz.u = *(const unsigned long long*)&zbias[(size_t)h * SS + ro];
            float4 bb = *(const float4*)&beta[(size_t)b * SS + ro];
            sc[ii][0] = b2f(zz.hh[0]) + bb.x;
            sc[ii][1] = b2f(zz.hh[1]) + bb.y;
            sc[ii][2] = b2f(zz.hh[2]) + bb.z;
            sc[ii][3] = b2f(zz.hh[3]) + bb.w;
        }
        #pragma unroll
        for (int d = 0; d < DD; d++) {
            float4 qa4 = *(const float4*)&Qt[d][ig * 4];
            float4 ka4 = *(const float4*)&Kt[d][jg * 4];
            float qa[4] = {qa4.x, qa4.y, qa4.z, qa4.w};
            float ka[4] = {ka4.x, ka4.y, ka4.z, ka4.w};
            #pragma unroll
            for (int ii = 0; ii < 4; ii++)
                #pragma unroll
                for (int jj = 0; jj < 4; jj++)
                    sc[ii][jj] += qa[ii] * ka[jj];
        }
        // ---- online softmax (rows owned by 16 consecutive lanes)
        #pragma unroll
        for (int ii = 0; ii < 4; ii++) {
            int row = ig * 4 + ii;
            float mx = sc[ii][0];
            #pragma unroll
            for (int jj = 1; jj < 4; jj++) mx = fmaxf(mx, sc[ii][jj]);
            for (int off = 1; off < 16; off <<= 1) mx = fmaxf(mx, __shfl_xor(mx, off, 64));
            float mo = m_l[row];
            float mn = fmaxf(mo, mx);
            float al = __expf(mo - mn);
            float ps = 0.f;
            #pragma unroll
            for (int jj = 0; jj < 4; jj++) {
                sc[ii][jj] = __expf(sc[ii][jj] - mn);
                ps += sc[ii][jj];
            }
            for (int off = 1; off < 16; off <<= 1) ps += __shfl_xor(ps, off, 64);
            if (jg == 0) {
                m_l[row] = mn;
                al_l[row] = al;
                l_l[row] = l_l[row] * al + ps;
            }
        }
        // write P transposed [j][i]
        #pragma unroll
        for (int jj = 0; jj < 4; jj++) {
            float4 pv = make_float4(sc[0][jj], sc[1][jj], sc[2][jj], sc[3][jj]);
            *(float4*)&Pt[jg * 4 + jj][ig * 4] = pv;
        }
        __syncthreads();
        // ---- PV accumulate (2 rows x 4 d per thread)
        float a0 = al_l[ig2 * 2], a1 = al_l[ig2 * 2 + 1];
        #pragma unroll
        for (int dd = 0; dd < 4; dd++) { O[0][dd] *= a0; O[1][dd] *= a1; }
        for (int j = 0; j < 64; j++) {
            float p0 = Pt[j][ig2 * 2], p1 = Pt[j][ig2 * 2 + 1];
            float4 vv4 = *(const float4*)&Vt[j][dg * 4];
            float vv[4] = {vv4.x, vv4.y, vv4.z, vv4.w};
            #pragma unroll
            for (int dd = 0; dd < 4; dd++) { O[0][dd] += p0 * vv[dd]; O[1][dd] += p1 * vv[dd]; }
        }
        __syncthreads();
    }
    float r0 = 1.0f / l_l[ig2 * 2];
    float r1 = 1.0f / l_l[ig2 * 2 + 1];
    size_t base = ((size_t)b * SQ + qt * 64 + ig2 * 2) * CS + h * DD + dg * 4;
    float* o0 = attn_out + base;
    *(float4*)o0 = make_float4(O[0][0] * r0, O[0][1] * r0, O[0][2] * r0, O[0][3] * r0);
    *(float4*)(o0 + CS) = make_float4(O[1][0] * r1, O[1][1] * r1, O[1][2] * r1, O[1][3] * r1);
}

// ---------------------------------------------------------------- k_gemm_out
// out[r,c] = (A @ w_o + b_o[c]) * gate[b,c]   (fp32 out)
__global__ __launch_bounds__(256) void k_gemm_out(const float* A, const float* W,
                                                  const float* b_o, const float* emb,
                                                  float* out) {
    __shared__ float As[16][68];
    __shared__ float Bs[16][68];
    int t = threadIdx.x;
    int m0g = blockIdx.x * 64;
    int n0g = blockIdx.y * 64;
    int mg = t >> 4, ng = t & 15;
    float acc[4][4] = {};
    for (int k0 = 0; k0 < CS; k0 += 16) {
        {
            int kk = t & 15, mm = t >> 4;
            #pragma unroll
            for (int r = 0; r < 4; r++)
                As[kk][mm + r * 16] = A[(size_t)(m0g + mm + r * 16) * CS + k0 + kk];
            int nn = (t & 15) * 4, kb = t >> 4;
            float4 w4 = *(const float4*)&W[(size_t)(k0 + kb) * CS + n0g + nn];
            *(float4*)&Bs[kb][nn] = w4;
        }
        __syncthreads();
        #pragma unroll
        for (int kk = 0; kk < 16; kk++) {
            float4 a4 = *(const float4*)&As[kk][mg * 4];
            float4 b4 = *(const float4*)&Bs[kk][ng * 4];
            float a[4] = {a4.x, a4.y, a4.z, a4.w};
            float bv[4] = {b4.x, b4.y, b4.z, b4.w};
            #pragma unroll
            for (int ii = 0; ii < 4; ii++)
                #pragma unroll
                for (int jj = 0; jj < 4; jj++)
                    acc[ii][jj] += a[ii] * bv[jj];
        }
        __syncthreads();
    }
    #pragma unroll
    for (int ii = 0; ii < 4; ii++) {
        int r = m0g + mg * 4 + ii;
        int b = r >> 10;
        int c0 = n0g + ng * 4;
        const float* gt = emb + (size_t)b * 3 * CS + 2 * CS;
        float4 o4;
        o4.x = (acc[ii][0] + b_o[c0 + 0]) * gt[c0 + 0];
        o4.y = (acc[ii][1] + b_o[c0 + 1]) * gt[c0 + 1];
        o4.z = (acc[ii][2] + b_o[c0 + 2]) * gt[c0 + 2];
        o4.w = (acc[ii][3] + b_o[c0 + 3]) * gt[c0 + 3];
        *(float4*)&out[(size_t)r * CS + c0] = o4;
    }
}

// ---------------------------------------------------------------- launch
extern "C" void kernel_launch(void* const* d_in, const int* in_sizes, int n_in,
                              void* d_out, int out_size, void* d_ws, size_t ws_size,
                              hipStream_t stream) {
    const float* bs      = (const float*)d_in[0];
    const float* z       = (const float*)d_in[1];
    const float* t       = (const float*)d_in[2];
    const float* beta    = (const float*)d_in[3];
    const int*   z_mask  = (const int*)d_in[4];
    const float* w_adaln = (const float*)d_in[5];
    const float* b_adaln = (const float*)d_in[6];
    const float* ln_z_w  = (const float*)d_in[7];
    const float* ln_z_b  = (const float*)d_in[8];
    const float* w_q     = (const float*)d_in[9];
    const float* w_k     = (const float*)d_in[10];
    const float* w_v     = (const float*)d_in[11];
    const float* w_z     = (const float*)d_in[12];
    const float* rms_q_w = (const float*)d_in[13];
    const float* rms_k_w = (const float*)d_in[14];
    const float* w_o     = (const float*)d_in[15];
    const float* b_o     = (const float*)d_in[16];
    float* out = (float*)d_out;

    char* ws = (char*)d_ws;
    const size_t SZ_QKV = (size_t)2 * SQ * CS * 4;   // 6291456
    float* emb   = (float*)(ws);                      // 2*2304*4 = 18432
    float* bsn   = (float*)(ws + 32768);
    float* qbuf  = (float*)(ws + 32768 + SZ_QKV);
    float* kbuf  = (float*)(ws + 32768 + 2 * SZ_QKV);
    float* vbuf  = (float*)(ws + 32768 + 3 * SZ_QKV);
    float* attn  = (float*)(ws + 32768 + 4 * SZ_QKV);
    bf16*  zbias = (bf16*)(ws + 32768 + 5 * SZ_QKV);  // 24*1024*1024*2 = 50331648

    k_adaln<<<dim3(9, 2), 256, 0, stream>>>(t, w_adaln, b_adaln, emb);
    k_bsnorm<<<2048, 256, 0, stream>>>(bs, emb, bsn);
    k_gemm_qkv<<<dim3(32, 12), 256, 0, stream>>>(bsn, w_q, qbuf);
    k_gemm_qkv<<<dim3(32, 12), 256, 0, stream>>>(bsn, w_k, kbuf);
    k_gemm_qkv<<<dim3(32, 12), 256, 0, stream>>>(bsn, w_v, vbuf);
    k_rms<<<6144, 256, 0, stream>>>(qbuf, rms_q_w);
    k_rms<<<6144, 256, 0, stream>>>(kbuf, rms_k_w);
    k_zbias<<<4096, 256, 0, stream>>>(z, z_mask, w_z, ln_z_w, ln_z_b, zbias);
    k_attn<<<dim3(16, 48), 256, 0, stream>>>(qbuf, kbuf, vbuf, zbias, beta, attn);
    k_gemm_out<<<dim3(32, 12), 256, 0, stream>>>(attn, w_o, b_o, emb, out);
}